// Round 12
// baseline (245.910 us; speedup 1.0000x reference)
//
#include <hip/hip_runtime.h>

// Transformer-XL relative multi-head attention + LayerNorm.
// Inputs/outputs fp32; internal MFMA compute in bf16.
// B=2, H=16, D=64, E=1024, QL=1024, ML=1024, KLEN=2048.
// rel_shift identity: unmasked (j<=i+ML): BDshift[i,j] = BD[i, j-i+QL-1].
// R27: exp2 fold (attn S-chain VALU trim). R26 zone-reorder WORKED
//   (243.3->239.3; proj out of top-5). attn now top at 64.0us,
//   latency-bound (Mfma 12.6/VALU 34/HBM 4%); serial S-chain includes
//   16x __expf = v_mul(log2e)+v_exp each. Fold log2e into proj zone-0
//   scale (0.03125 -> 0.03125*log2e; AC and BD inherit it through
//   MFMA), attn uses exp2f -> bare v_exp_f32. Same softmax up to bf16
//   rounding of rescaled Q. Everything else frozen.
// R26: proj_k zone order z3,z0,z1,z2 (heavy-first tail trim, -4us).
// R22: proj_k body FROZEN at R9 (R14/R19/R21 regressed).
// R20: attn_k XCD-local balanced decode (FETCH 93->16MB).
// R18: setprio on S-compute; gemm_o split-K x4.
// R17: 8-wave producer/consumer attn (S: softmax -> UB dbuf; O: PV).

typedef __bf16 bf16;
typedef __bf16 bf16x4 __attribute__((ext_vector_type(4)));
typedef __bf16 bf16x8 __attribute__((ext_vector_type(8)));
typedef float f32x4 __attribute__((ext_vector_type(4)));

#define MFMA16(a, b, c) __builtin_amdgcn_mfma_f32_16x16x32_bf16((a), (b), (c), 0, 0, 0)

constexpr int E = 1024;
constexpr int NH = 16;
constexpr int DH = 64;
constexpr int QL = 1024;
constexpr int ML = 1024;
constexpr int KLEN = 2048;
// 1/sqrt(E) * log2(e): attn computes exp2(scaled logits) = exp(logits/32)
constexpr float QSCALE = 0.03125f * 1.44269504088896340736f;

// async 16B global->LDS. LDS dest is wave-uniform base + lane*16.
__device__ __forceinline__ void ldg2lds16(const bf16* g, bf16* l) {
    __builtin_amdgcn_global_load_lds(
        (const __attribute__((address_space(1))) unsigned int*)g,
        (__attribute__((address_space(3))) unsigned int*)l, 16, 0, 0);
}

// read a b128 fragment from an unpadded 64-col swizzled tile.
// physical 16B-chunk = logical chunk ^ (row & 7).
__device__ __forceinline__ bf16x8 frag8(const bf16* t, int row, int ch) {
    return *(const bf16x8*)(t + row * 64 + ((ch ^ (row & 7)) << 3));
}

// ---------------------------------------------------------------- pre
// R24: blocks 0..1279: 5 weight transposes, 64x64 tiles
//   (WT[n][k] = bf16(W[k][n]) — exact copy, bit-identical any tiling).
// blocks 1280..1791: cat, 8 rows per block.
__global__ void pre_k(const float* __restrict__ Wq, const float* __restrict__ Wk,
                      const float* __restrict__ Wv, const float* __restrict__ Wr,
                      const float* __restrict__ Wo, const float* __restrict__ member,
                      const float* __restrict__ w, bf16* __restrict__ WqT,
                      bf16* __restrict__ WkT, bf16* __restrict__ WvT,
                      bf16* __restrict__ WrT, bf16* __restrict__ WoT,
                      bf16* __restrict__ cat) {
    const int id = blockIdx.x;
    const int tid = threadIdx.x;
    __shared__ float t[64][65];
    if (id < 1280) {
        const float* W; bf16* WT;
        switch (id >> 8) {
            case 0: W = Wq; WT = WqT; break;
            case 1: W = Wk; WT = WkT; break;
            case 2: W = Wv; WT = WvT; break;
            case 3: W = Wr; WT = WrT; break;
            default: W = Wo; WT = WoT; break;
        }
        int xy = id & 255;                       // 16x16 tiles of 64x64
        int bx = (xy & 15) * 64, by = (xy >> 4) * 64;
        int x4 = (tid & 15) * 4, yy = tid >> 4;  // 16 col-quads x 16 rows
        for (int ry = 0; ry < 4; ++ry) {
            int row = ry * 16 + yy;
            float4 f = *(const float4*)(W + (size_t)(by + row) * E + bx + x4);
            t[row][x4 + 0] = f.x; t[row][x4 + 1] = f.y;
            t[row][x4 + 2] = f.z; t[row][x4 + 3] = f.w;
        }
        __syncthreads();
        for (int ry = 0; ry < 4; ++ry) {
            int r = ry * 16 + yy;
            bf16x4 o;
            o[0] = (bf16)t[x4 + 0][r]; o[1] = (bf16)t[x4 + 1][r];
            o[2] = (bf16)t[x4 + 2][r]; o[3] = (bf16)t[x4 + 3][r];
            *(bf16x4*)(WT + (size_t)(bx + r) * E + by + x4) = o;
        }
    } else {
        int row0 = (id - 1280) * 8;
        for (int rr = 0; rr < 8; ++rr) {
            int row = row0 + rr;
            int b = row >> 11, jj = row & 2047;
            const float* src = (jj < ML) ? member + ((size_t)(b * ML + jj)) * E
                                         : w + ((size_t)(b * QL + (jj - ML))) * E;
            float4 f = *(const float4*)(src + tid * 4);
            bf16x4 o;
            o[0] = (bf16)f.x; o[1] = (bf16)f.y; o[2] = (bf16)f.z; o[3] = (bf16)f.w;
            *(bf16x4*)(cat + (size_t)row * E + tid * 4) = o;
        }
    }
}

// ---------------------------------------------------------------- projections
// EXACT R9 body (FROZEN). Single-buffer two-barrier staging.
// R26 decode: heavy zones first. id<128: zone3 (R->RRh); 128..255: zone0
// (Q->Qw/Qr); 256..511: zone1 (K->Kh); 512..767: zone2 (V->Vt).
// R27: zone-0 scale folds log2e (QSCALE) so attn can use raw exp2.
__global__ __launch_bounds__(256) void proj_k(
    const bf16* __restrict__ cat, const float* __restrict__ r,
    const bf16* __restrict__ WqT, const bf16* __restrict__ WkT,
    const bf16* __restrict__ WvT, const bf16* __restrict__ WrT,
    const float* __restrict__ rwb, const float* __restrict__ rrb,
    bf16* __restrict__ Qw, bf16* __restrict__ Qr, bf16* __restrict__ Kh,
    bf16* __restrict__ Vt, bf16* __restrict__ RRh) {
    __shared__ __align__(16) bf16 As[128 * 64];
    __shared__ __align__(16) bf16 Bs[128 * 64];
    const int tid = threadIdx.x;
    const int wave = tid >> 6, lane = tid & 63, quad = lane >> 4, l16 = lane & 15;

    int id = blockIdx.x, zone, base;
    if (id < 128) { zone = 3; base = 0; }
    else if (id < 256) { zone = 0; base = 128; }
    else if (id < 512) { zone = 1; base = 256; }
    else { zone = 2; base = 512; }
    const int lid = id - base;
    const int bn = (lid & 7) * 128, bm = (lid >> 3) * 128;
    const bf16* Bt = (zone == 0) ? WqT : (zone == 1) ? WkT : (zone == 2) ? WvT : WrT;
    const int wm = (wave >> 1) * 64, wn = (wave & 1) * 64;

    f32x4 acc[4][4] = {};

    for (int kk = 0; kk < E; kk += 64) {
        if (zone == 3) {  // fp32 A: manual convert+write (swizzled slots)
            int srw = tid >> 3, cch = tid & 7;
            for (int c = 0; c < 4; ++c) {
                int row = c * 32 + srw;
                const float* ap = r + (size_t)(bm + row) * E + kk + cch * 8;
                float4 f0 = *(const float4*)ap;
                float4 f1 = *(const float4*)(ap + 4);
                bf16x8 v;
                v[0] = (bf16)f0.x; v[1] = (bf16)f0.y; v[2] = (bf16)f0.z; v[3] = (bf16)f0.w;
                v[4] = (bf16)f1.x; v[5] = (bf16)f1.y; v[6] = (bf16)f1.z; v[7] = (bf16)f1.w;
                *(bf16x8*)(As + row * 64 + ((cch ^ (row & 7)) << 3)) = v;
            }
        } else {
            for (int issue = 0; issue < 4; ++issue) {
                int q = (issue * 4 + wave) * 64 + lane;
                int row = q >> 3, cs = (q & 7) ^ ((q >> 3) & 7);
                int gm = bm + row;
                const bf16* ap;
                if (zone == 0) {
                    int b = gm >> 10;
                    ap = cat + ((size_t)(b * 2048 + 1024 + (gm & 1023))) * E;
                } else {
                    ap = cat + (size_t)gm * E;
                }
                ldg2lds16(ap + kk + cs * 8, As + (issue * 4 + wave) * 512);
            }
        }
        for (int issue = 0; issue < 4; ++issue) {
            int q = (issue * 4 + wave) * 64 + lane;
            int row = q >> 3, cs = (q & 7) ^ ((q >> 3) & 7);
            ldg2lds16(Bt + (size_t)(bn + row) * E + kk + cs * 8,
                      Bs + (issue * 4 + wave) * 512);
        }
        __syncthreads();
        for (int ks = 0; ks < 64; ks += 32) {
            bf16x8 af[4], bfr[4];
            for (int mt = 0; mt < 4; ++mt)
                af[mt] = frag8(As, wm + mt * 16 + l16, (ks >> 3) + quad);
            for (int nt = 0; nt < 4; ++nt)
                bfr[nt] = frag8(Bs, wn + nt * 16 + l16, (ks >> 3) + quad);
            for (int mt = 0; mt < 4; ++mt)
                for (int nt = 0; nt < 4; ++nt)
                    acc[mt][nt] = MFMA16(af[mt], bfr[nt], acc[mt][nt]);
        }
        __syncthreads();
    }

    if (zone == 2) {
        // Vt[b][h][d][j]: per-wave 64x64 swizzled LDS transpose, then b128 stores.
        bf16* buf = ((wave < 2) ? As : Bs) + (wave & 1) * 4096;
        for (int mt = 0; mt < 4; ++mt)
            for (int nt = 0; nt < 4; ++nt)
                for (int rr = 0; rr < 4; ++rr) {
                    int lr = mt * 16 + quad * 4 + rr;  // local j
                    int lc = nt * 16 + l16;            // local d
                    buf[lr * 64 + (((lc >> 3) ^ (lr & 7)) << 3) + (lc & 7)] =
                        (bf16)acc[mt][nt][rr];
                }
        int h = (bn + wn) >> 6;
        int gmw = bm + wm;
        int b = gmw >> 11, jb = gmw & 2047;
        for (int dp = 0; dp < 8; ++dp) {
            int dl = dp * 8 + (lane >> 3);
            int jl = (lane & 7) * 8;
            bf16x8 tmp;
            for (int jj = 0; jj < 8; ++jj) {
                int rw = jl + jj;
                tmp[jj] = buf[rw * 64 + (((dl >> 3) ^ (rw & 7)) << 3) + (dl & 7)];
            }
            *(bf16x8*)(Vt + (((size_t)(b * NH + h) * DH + dl) * KLEN) + jb + jl) = tmp;
        }
        return;
    }

    for (int mt = 0; mt < 4; ++mt)
        for (int nt = 0; nt < 4; ++nt)
            for (int rr = 0; rr < 4; ++rr) {
                int row = bm + wm + mt * 16 + quad * 4 + rr;
                int col = bn + wn + nt * 16 + l16;
                float v = acc[mt][nt][rr];
                if (zone == 0) {
                    int b = row >> 10, i = row & 1023;
                    int h = col >> 6, d = col & 63;
                    size_t o = (((size_t)(b * NH + h) * QL) + i) * DH + d;
                    Qw[o] = (bf16)((v + rwb[col]) * QSCALE);  // 1/sqrt(E)*log2e
                    Qr[o] = (bf16)((v + rrb[col]) * QSCALE);
                } else if (zone == 1) {
                    int b = row >> 11, j = row & 2047;
                    int h = col >> 6, d = col & 63;
                    Kh[(((size_t)(b * NH + h) * KLEN) + j) * DH + d] = (bf16)v;
                } else {
                    int h = col >> 6, d = col & 63;
                    RRh[(((size_t)h * KLEN) + row) * DH + d] = (bf16)v;
                }
            }
}

// ---------------------------------------------------------------- attention
// R20: R18 schedule (verified) + XCD-local balanced decode.
// 512 blocks x 512 thr; 8-wave producer/consumer (S: softmax, O: PV).
// Decode: xcd=id&7 owns combos xcd*4..+3 (4 heads, ~4MB K/V/RR = L2-fit).
// v6=id>>3: cl=v6&3 (combo lane), qi=v6>>2; qt0 = qi<8 ? qi : 23-qi;
// qt = (cl&1) ? 15-qt0 : qt0. Bijective per (xcd,cl); co-resident pairs
// sum to 49 phases under BOTH (v6,v6+1) and (v6,v6+32) dispatch pairings.
// Phase p: stage K(p+1), RR(c+p+2), V(p); S: MFMA(p)+softmax -> UB[p&1];
// O: PV(p-1) from UB/Vs[(p-1)&1]. One barrier per phase.
// R27: logits carry log2e (QSCALE) -> exp2f = bare v_exp_f32.
__global__ __launch_bounds__(512, 4) void attn_k(
    const bf16* __restrict__ Qw, const bf16* __restrict__ Qr,
    const bf16* __restrict__ Kh, const bf16* __restrict__ Vt,
    const bf16* __restrict__ RRh, bf16* __restrict__ AttO) {
    __shared__ __align__(16) bf16 Ks[2][64 * 64];
    __shared__ __align__(16) bf16 Vs[2][64 * 64];
    __shared__ __align__(16) bf16 RRing[3][64 * 64];
    __shared__ __align__(16) bf16 UB[2][4][16 * 88];  // P dbuf (+linv stash)

    const int tid = threadIdx.x;
    const int wave = tid >> 6, lane = tid & 63, quad = lane >> 4, l16 = lane & 15;
    const int id = blockIdx.x;
    // XCD-aware decode (hw xcd = blockIdx % 8 round-robin; perf-only).
    const int xcd = id & 7;
    const int v6 = id >> 3;       // 0..63 within XCD
    const int cl = v6 & 3;        // combo lane
    const int qi = v6 >> 2;       // 0..15
    const int qt0 = (qi < 8) ? qi : 23 - qi;
    const int qt = (cl & 1) ? 15 - qt0 : qt0;
    const int combo = xcd * 4 + cl;  // 0..31 = (b,h)
    const int b = combo >> 4, h = combo & 15;
    const int i0 = qt * 64;
    const bool isS = wave < 4;
    const int sw = isS ? wave : wave - 4;  // q-row group 0..3 within block

    const bf16* Qwb = Qw + ((size_t)(b * NH + h) * QL) * DH;
    const bf16* Qrb = Qr + ((size_t)(b * NH + h) * QL) * DH;
    const bf16* Kb = Kh + ((size_t)(b * NH + h) * KLEN) * DH;
    const bf16* Vb = Vt + ((size_t)(b * NH + h) * DH) * KLEN;  // [d][j]
    const bf16* Rb = RRh + ((size_t)h * KLEN) * DH;

    bf16x8 qw0, qw1, qr0, qr1;
    if (isS) {
        int i = i0 + sw * 16 + l16;
        qw0 = *(const bf16x8*)(Qwb + (size_t)i * DH + quad * 8);
        qw1 = *(const bf16x8*)(Qwb + (size_t)i * DH + 32 + quad * 8);
        qr0 = *(const bf16x8*)(Qrb + (size_t)i * DH + quad * 8);
        qr1 = *(const bf16x8*)(Qrb + (size_t)i * DH + 32 + quad * 8);
    }

    float lpart[4] = {0.f, 0.f, 0.f, 0.f};
    f32x4 oacc[4] = {};

    const int ntiles = qt + 17;
    const int cbase = 15 - qt;  // global RR chunk of window start at t=0
    const int ptbase = 3 - sw;

    // per-wave 512-element (1KB) DMA slices; all 8 waves participate.
    auto stageK = [&](int t) {
        int q = wave * 64 + lane;
        int row = q >> 3, cs = (q & 7) ^ (row & 7);
        ldg2lds16(Kb + (size_t)(t * 64 + row) * DH + cs * 8,
                  Ks[t & 1] + wave * 512);
    };
    auto stageV = [&](int t) {
        int q = wave * 64 + lane;
        int row = q >> 3, cs = (q & 7) ^ (row & 7);
        ldg2lds16(Vb + (size_t)row * KLEN + t * 64 + cs * 8,
                  Vs[t & 1] + wave * 512);
    };
    auto stageRR = [&](int c) {
        int q = wave * 64 + lane;
        int row = q >> 3, cs = (q & 7) ^ (row & 7);
        int pr = c * 64 + row;
        pr = pr > KLEN - 1 ? KLEN - 1 : pr;  // clamped rows feed masked cols
        ldg2lds16(Rb + (size_t)pr * DH + cs * 8, RRing[c % 3] + wave * 512);
    };

    stageK(0);
    stageRR(cbase);
    stageRR(cbase + 1);
    __syncthreads();

    for (int p = 0; p <= ntiles; ++p) {
        if (p + 1 < ntiles) {
            stageK(p + 1);
            stageRR(cbase + p + 2);
        }
        if (p < ntiles) stageV(p);

        if (isS) {
            __builtin_amdgcn_s_setprio(1);
            if (p < ntiles) {
                const bf16* Kt = Ks[p & 1];
                const bf16* Rlo = RRing[(cbase + p) % 3];
                const bf16* Rhi = RRing[(cbase + p + 1) % 3];

                // BD = Qr @ RRwindow^T (this wave's 5 pt tiles) -> registers
                f32x4 bacc[5];
                for (int pi = 0; pi < 5; ++pi) {
                    int pt = ptbase + pi;
                    const bf16* Rsrc = (pt < 4) ? Rlo : Rhi;
                    int rrow = (pt & 3) * 16 + l16;
                    f32x4 a = {};
                    a = MFMA16(qr0, frag8(Rsrc, rrow, quad), a);
                    a = MFMA16(qr1, frag8(Rsrc, rrow, 4 + quad), a);
                    bacc[pi] = a;
                }

                // AC = Qw @ K^T
                f32x4 sacc[4];
                for (int nt = 0; nt < 4; ++nt) {
                    f32x4 a = {};
                    a = MFMA16(qw0, frag8(Kt, nt * 16 + l16, quad), a);
                    a = MFMA16(qw1, frag8(Kt, nt * 16 + l16, 4 + quad), a);
                    sacc[nt] = a;
                }

                // p = exp2(AC+BD) (log2e folded upstream); BD rel-shift gather.
                float sv[4][4];
                const bool lastt = (p == ntiles - 1);
                for (int rr = 0; rr < 4; ++rr) {
                    const int lr = quad * 4 + rr;
                    const int srcl = quad * 16 + ((l16 - lr - 1) & 15);
                    float g[5];
                    for (int pi = 0; pi < 5; ++pi) g[pi] = __shfl(bacc[pi][rr], srcl);
                    const bool hi = (l16 > lr);
                    for (int nt = 0; nt < 4; ++nt) {
                        float bdv = hi ? g[nt + 1] : g[nt];
                        float pv = exp2f(sacc[nt][rr] + bdv);
                        if (lastt) {
                            int i = i0 + sw * 16 + lr;
                            int j = p * 64 + nt * 16 + l16;
                            if (j > i + ML) pv = 0.f;
                        }
                        sv[nt][rr] = pv;
                        lpart[rr] += pv;
                    }
                }

                // P: C-layout -> UB[p&1] (A-layout source for O-waves)
                bf16* UBd = UB[p & 1][sw];
                for (int nt = 0; nt < 4; ++nt)
                    for (int rr = 0; rr < 4; ++rr)
                        UBd[(quad * 4 + rr) * 88 + nt * 16 + l16] = (bf16)sv[nt][rr];
            } else {
                // final phase: deferred l reduction -> linv stash in dead UB half
                float* lp = (float*)(&UB[ntiles & 1][sw][0]);
                for (int rr = 0; rr < 4; ++rr) {
                    float v = lpart[rr];
                    v += __shfl_xor(v, 1);
                    v += __shfl_xor(v, 2);
                    v += __shfl_xor(v, 4);
                    v += __shfl_xor(v, 8);
                    lp[lane * 4 + rr] = 1.f / v;
                }
            }
            __builtin_amdgcn_s_setprio(0);
        } else if (p >= 1) {
            // O-waves: PV for tile p-1
            const bf16* Vl = Vs[(p - 1) & 1];
            const bf16* UBs = UB[(p - 1) & 1][sw];
            for (int c = 0; c < 2; ++c) {
                bf16x8 pa = *(const bf16x8*)(&UBs[l16 * 88 + c * 32 + quad * 8]);
                for (int nt = 0; nt < 4; ++nt) {
                    bf16x8 vb = frag8(Vl, nt * 16 + l16, c * 4 + quad);
                    oacc[nt] = MFMA16(pa, vb, oacc[nt]);
                }
            }
        }
        __syncthreads();  // DMA drain + UB handoff + buffer WAR
    }

    if (!isS) {
        const float* lp = (const float*)(&UB[ntiles & 1][sw][0]);
        for (int nt = 0; nt < 4; ++nt)
            for (int rr = 0; rr < 4; ++rr) {
                int i = i0 + sw * 16 + quad * 4 + rr;
                int d = nt * 16 + l16;
                AttO[((size_t)(b * QL + i)) * E + h * DH + d] =
                    (bf16)(oacc[nt][rr] * lp[lane * 4 + rr]);
            }
    }
}

// ---------------------------------------------------------------- out proj
// R18: split-K x4. 512 blocks -> 2 blocks/CU. z in 0..3 computes K-slice
// z*256..+256 -> partial Xp[z] (fp32); z==3 partial over dead WqT..WrT.
__global__ __launch_bounds__(256) void gemm_o(
    const bf16* __restrict__ A, const bf16* __restrict__ Bt,
    float* __restrict__ Xp, float* __restrict__ Xp3) {
    __shared__ __align__(16) bf16 As[128 * 64];
    __shared__ __align__(16) bf16 Bs[128 * 64];
    const int tid = threadIdx.x;
    const int wave = tid >> 6, lane = tid & 63, quad = lane >> 4, l16 = lane & 15;
    const int bm = blockIdx.y * 128, bn = blockIdx.x * 128;
    const int kbase = blockIdx.z * 256;
    const int wm = (wave >> 1) * 64, wn = (wave & 1) * 64;

    f32x4 acc[4][4] = {};

    for (int s = 0; s < 4; ++s) {
        const int kk = kbase + s * 64;
        for (int issue = 0; issue < 4; ++issue) {
            int q = (issue * 4 + wave) * 64 + lane;
            int row = q >> 3, cs = (q & 7) ^ ((q >> 3) & 7);
            ldg2lds16(A + (size_t)(bm + row) * E + kk + cs * 8,
                      As + (issue * 4 + wave) * 512);
            ldg2lds16(Bt + (size_t)(bn + row) * E + kk + cs * 8,
                      Bs + (issue * 4 + wave) * 512);
        }
        __syncthreads();
        for (int ks = 0; ks < 64; ks += 32) {
            bf16x8 af[4], bfr[4];
            for (int mt = 0; mt < 4; ++mt)
                af[mt] = frag8(As, wm + mt * 16 + l16, (ks >> 3) + quad);
            for (int nt = 0; nt < 4; ++nt)
                bfr[nt] = frag8(Bs, wn + nt * 16 + l16, (ks >> 3) + quad);
            for (int mt = 0; mt < 4; ++mt)
                for (int nt = 0; nt < 4; ++nt)
                    acc[mt][nt] = MFMA16(af[mt], bfr[nt], acc[mt][nt]);
        }
        __syncthreads();
    }

    float* Xz = (blockIdx.z == 3) ? Xp3
                                  : Xp + (size_t)blockIdx.z * 2048 * 1024;
    for (int mt = 0; mt < 4; ++mt)
        for (int nt = 0; nt < 4; ++nt)
            for (int rr = 0; rr < 4; ++rr) {
                int row = bm + wm + mt * 16 + quad * 4 + rr;
                int col = bn + wn + nt * 16 + l16;
                Xz[(size_t)row * E + col] = acc[mt][nt][rr];
            }
}

// ---------------------------------------------------------------- layernorm
// x = Xp0 + Xp1 + Xp2 + Xp3 + resid(w); out = LN(x)*gamma+beta
// R24: 512 blocks x 4 rows (per-row math identical to R23; float4 path).
__global__ __launch_bounds__(256) void ln_k(const float* __restrict__ Xp,
                                            const float* __restrict__ Xp3,
                                            const float* __restrict__ resid,
                                            const float* __restrict__ gamma,
                                            const float* __restrict__ beta,
                                            float* __restrict__ out) {
    const int tid = threadIdx.x;
    __shared__ float rs[4], rq[4];
    const int wave = tid >> 6, lane = tid & 63;
    float4 g = ((const float4*)gamma)[tid];
    float4 bt = ((const float4*)beta)[tid];
    for (int it = 0; it < 4; ++it) {
        const int row = blockIdx.x * 4 + it;
        const float4* x0 = (const float4*)(Xp + (size_t)row * E);
        const float4* x1 = (const float4*)(Xp + (size_t)2048 * 1024 + (size_t)row * E);
        const float4* x2 = (const float4*)(Xp + (size_t)2 * 2048 * 1024 + (size_t)row * E);
        const float4* x3 = (const float4*)(Xp3 + (size_t)row * E);
        const float4* xr = (const float4*)(resid + (size_t)row * E);
        float4 a0 = x0[tid], a1 = x1[tid], a2 = x2[tid], a3 = x3[tid], ar = xr[tid];
        float4 v;
        v.x = a0.x + a1.x + a2.x + a3.x + ar.x;
        v.y = a0.y + a1.y + a2.y + a3.y + ar.y;
        v.z = a0.z + a1.z + a2.z + a3.z + ar.z;
        v.w = a0.w + a1.w + a2.w + a3.w + ar.w;
        float s = v.x + v.y + v.z + v.w;
        float q = v.x * v.x + v.y * v.y + v.z * v.z + v.w * v.w;
        for (int off = 32; off > 0; off >>= 1) {
            s += __shfl_down(s, off);
            q += __shfl_down(q, off);
        }
        if (lane == 0) { rs[wave] = s; rq[wave] = q; }
        __syncthreads();
        float S = rs[0] + rs[1] + rs[2] + rs[3];
        float Q = rq[0] + rq[1] + rq[2] + rq[3];
        float mean = S * (1.f / E);
        float var = fmaxf(Q * (1.f / E) - mean * mean, 0.f);
        float rstd = rsqrtf(var + 1e-3f);
        float4 o;
        o.x = (v.x - mean) * rstd * g.x + bt.x;
        o.y = (v.y - mean) * rstd * g.y + bt.y;
        o.z = (v.z - mean) * rstd * g.z + bt.z;
        o.w = (v.w - mean) * rstd * g.w + bt.w;
        ((float4*)(out + (size_t)row * E))[tid] = o;
        __syncthreads();  // rs/rq reuse across rows
    }
}

// ---------------------------------------------------------------- launch
extern "C" void kernel_launch(void* const* d_in, const int* in_sizes, int n_in,
                              void* d_out, int out_size, void* d_ws,
                              size_t ws_size, hipStream_t stream) {
    (void)in_sizes; (void)n_in; (void)out_size; (void)ws_size;
    const float* w = (const float*)d_in[0];
    const float* r = (const float*)d_in[1];
    const float* rwb = (const float*)d_in[3];
    const float* rrb = (const float*)d_in[4];
    const float* member = (const float*)d_in[5];
    const float* Wq = (const float*)d_in[6];
    const float* Wk = (const float*)d_in[7];
    const float* Wv = (const float*)d_in[8];
    const float* Wr = (const float*)d_in[9];
    const float* Wo = (const float*)d_in[10];
    const float* gamma = (const float*)d_in[11];
    const float* beta = (const float*)d_in[12];
    float* out = (float*)d_out;

    char* ws = (char*)d_ws;
    const size_t MB = 1024 * 1024;
    bf16* WqT = (bf16*)(ws + 0 * MB);   // 0-8: WqT..WrT (dead after proj_k;
    bf16* WkT = (bf16*)(ws + 2 * MB);   //   reused as Xp3 by gemm_o)
    bf16* WvT = (bf16*)(ws + 4 * MB);
    bf16* WrT = (bf16*)(ws + 6 * MB);
    bf16* WoT = (bf16*)(ws + 8 * MB);   // live until gemm_o
    bf16* cat = (bf16*)(ws + 10 * MB);  // 10-18; dead after proj_k
    bf16* AttO = (bf16*)(ws + 14 * MB); // 14-18 (over cat 2nd half)
    bf16* Qw = (bf16*)(ws + 18 * MB);
    bf16* Qr = (bf16*)(ws + 22 * MB);
    float* Xp = (float*)(ws + 18 * MB); // 18-42: Xp z=0..2 (over Qw/Qr/Kh,
    bf16* Kh = (bf16*)(ws + 26 * MB);   //   dead after attn)
    bf16* Vt = (bf16*)(ws + 34 * MB);   // Vt dead after attn -> Xp z=2
    bf16* RRh = (bf16*)(ws + 42 * MB);
    float* Xp3 = (float*)(ws + 0 * MB); // z=3 partial over WqT..WrT
    // high-water: 46 MB (unchanged)

    pre_k<<<1792, 256, 0, stream>>>(Wq, Wk, Wv, Wr, Wo, member, w, WqT, WkT,
                                    WvT, WrT, WoT, cat);

    proj_k<<<768, 256, 0, stream>>>(cat, r, WqT, WkT, WvT, WrT, rwb, rrb, Qw,
                                    Qr, Kh, Vt, RRh);

    attn_k<<<512, 512, 0, stream>>>(Qw, Qr, Kh, Vt, RRh, AttO);

    gemm_o<<<dim3(8, 16, 4), 256, 0, stream>>>(AttO, WoT, Xp, Xp3);
    ln_k<<<512, 256, 0, stream>>>(Xp, Xp3, w, gamma, beta, out);
}

// Round 14
// 236.684 us; speedup vs baseline: 1.0390x; 1.0390x over previous
//
#include <hip/hip_runtime.h>

// Transformer-XL relative multi-head attention + LayerNorm.
// Inputs/outputs fp32; internal MFMA compute in bf16.
// B=2, H=16, D=64, E=1024, QL=1024, ML=1024, KLEN=2048.
// rel_shift identity: unmasked (j<=i+ML): BDshift[i,j] = BD[i, j-i+QL-1].
// R29: RESUBMIT of R28 (round 13 hit GPUAcquisitionTimeout -> no data).
// R28: fix R27's regression (70.1us, VALUBusy UP 34->39): exp2f() is the
//   PRECISE libm entry (guarded, ~6 VALU ops) — not the bare instruction.
//   __expf was fast (v_mul+v_exp). Keep QSCALE fold; use
//   __builtin_amdgcn_exp2f -> single v_exp_f32 (input range |x|~few,
//   clean). Fallback if >=64us: revert fold to R26 (verified 239.3).
// R26: proj_k zone order z3,z0,z1,z2 (heavy-first tail trim, -4us).
// R22: proj_k body FROZEN at R9 (R14/R19/R21 regressed).
// R20: attn_k XCD-local balanced decode (FETCH 93->16MB).
// R18: setprio on S-compute; gemm_o split-K x4.
// R17: 8-wave producer/consumer attn (S: softmax -> UB dbuf; O: PV).

typedef __bf16 bf16;
typedef __bf16 bf16x4 __attribute__((ext_vector_type(4)));
typedef __bf16 bf16x8 __attribute__((ext_vector_type(8)));
typedef float f32x4 __attribute__((ext_vector_type(4)));

#define MFMA16(a, b, c) __builtin_amdgcn_mfma_f32_16x16x32_bf16((a), (b), (c), 0, 0, 0)

constexpr int E = 1024;
constexpr int NH = 16;
constexpr int DH = 64;
constexpr int QL = 1024;
constexpr int ML = 1024;
constexpr int KLEN = 2048;
// 1/sqrt(E) * log2(e): attn computes exp2(scaled logits) = exp(logits/32)
constexpr float QSCALE = 0.03125f * 1.44269504088896340736f;

// async 16B global->LDS. LDS dest is wave-uniform base + lane*16.
__device__ __forceinline__ void ldg2lds16(const bf16* g, bf16* l) {
    __builtin_amdgcn_global_load_lds(
        (const __attribute__((address_space(1))) unsigned int*)g,
        (__attribute__((address_space(3))) unsigned int*)l, 16, 0, 0);
}

// read a b128 fragment from an unpadded 64-col swizzled tile.
// physical 16B-chunk = logical chunk ^ (row & 7).
__device__ __forceinline__ bf16x8 frag8(const bf16* t, int row, int ch) {
    return *(const bf16x8*)(t + row * 64 + ((ch ^ (row & 7)) << 3));
}

// ---------------------------------------------------------------- pre
// R24: blocks 0..1279: 5 weight transposes, 64x64 tiles
//   (WT[n][k] = bf16(W[k][n]) — exact copy, bit-identical any tiling).
// blocks 1280..1791: cat, 8 rows per block.
__global__ void pre_k(const float* __restrict__ Wq, const float* __restrict__ Wk,
                      const float* __restrict__ Wv, const float* __restrict__ Wr,
                      const float* __restrict__ Wo, const float* __restrict__ member,
                      const float* __restrict__ w, bf16* __restrict__ WqT,
                      bf16* __restrict__ WkT, bf16* __restrict__ WvT,
                      bf16* __restrict__ WrT, bf16* __restrict__ WoT,
                      bf16* __restrict__ cat) {
    const int id = blockIdx.x;
    const int tid = threadIdx.x;
    __shared__ float t[64][65];
    if (id < 1280) {
        const float* W; bf16* WT;
        switch (id >> 8) {
            case 0: W = Wq; WT = WqT; break;
            case 1: W = Wk; WT = WkT; break;
            case 2: W = Wv; WT = WvT; break;
            case 3: W = Wr; WT = WrT; break;
            default: W = Wo; WT = WoT; break;
        }
        int xy = id & 255;                       // 16x16 tiles of 64x64
        int bx = (xy & 15) * 64, by = (xy >> 4) * 64;
        int x4 = (tid & 15) * 4, yy = tid >> 4;  // 16 col-quads x 16 rows
        for (int ry = 0; ry < 4; ++ry) {
            int row = ry * 16 + yy;
            float4 f = *(const float4*)(W + (size_t)(by + row) * E + bx + x4);
            t[row][x4 + 0] = f.x; t[row][x4 + 1] = f.y;
            t[row][x4 + 2] = f.z; t[row][x4 + 3] = f.w;
        }
        __syncthreads();
        for (int ry = 0; ry < 4; ++ry) {
            int r = ry * 16 + yy;
            bf16x4 o;
            o[0] = (bf16)t[x4 + 0][r]; o[1] = (bf16)t[x4 + 1][r];
            o[2] = (bf16)t[x4 + 2][r]; o[3] = (bf16)t[x4 + 3][r];
            *(bf16x4*)(WT + (size_t)(bx + r) * E + by + x4) = o;
        }
    } else {
        int row0 = (id - 1280) * 8;
        for (int rr = 0; rr < 8; ++rr) {
            int row = row0 + rr;
            int b = row >> 11, jj = row & 2047;
            const float* src = (jj < ML) ? member + ((size_t)(b * ML + jj)) * E
                                         : w + ((size_t)(b * QL + (jj - ML))) * E;
            float4 f = *(const float4*)(src + tid * 4);
            bf16x4 o;
            o[0] = (bf16)f.x; o[1] = (bf16)f.y; o[2] = (bf16)f.z; o[3] = (bf16)f.w;
            *(bf16x4*)(cat + (size_t)row * E + tid * 4) = o;
        }
    }
}

// ---------------------------------------------------------------- projections
// EXACT R9 body (FROZEN). Single-buffer two-barrier staging.
// R26 decode: heavy zones first. id<128: zone3 (R->RRh); 128..255: zone0
// (Q->Qw/Qr); 256..511: zone1 (K->Kh); 512..767: zone2 (V->Vt).
// R27: zone-0 scale folds log2e (QSCALE) so attn can use raw exp2.
__global__ __launch_bounds__(256) void proj_k(
    const bf16* __restrict__ cat, const float* __restrict__ r,
    const bf16* __restrict__ WqT, const bf16* __restrict__ WkT,
    const bf16* __restrict__ WvT, const bf16* __restrict__ WrT,
    const float* __restrict__ rwb, const float* __restrict__ rrb,
    bf16* __restrict__ Qw, bf16* __restrict__ Qr, bf16* __restrict__ Kh,
    bf16* __restrict__ Vt, bf16* __restrict__ RRh) {
    __shared__ __align__(16) bf16 As[128 * 64];
    __shared__ __align__(16) bf16 Bs[128 * 64];
    const int tid = threadIdx.x;
    const int wave = tid >> 6, lane = tid & 63, quad = lane >> 4, l16 = lane & 15;

    int id = blockIdx.x, zone, base;
    if (id < 128) { zone = 3; base = 0; }
    else if (id < 256) { zone = 0; base = 128; }
    else if (id < 512) { zone = 1; base = 256; }
    else { zone = 2; base = 512; }
    const int lid = id - base;
    const int bn = (lid & 7) * 128, bm = (lid >> 3) * 128;
    const bf16* Bt = (zone == 0) ? WqT : (zone == 1) ? WkT : (zone == 2) ? WvT : WrT;
    const int wm = (wave >> 1) * 64, wn = (wave & 1) * 64;

    f32x4 acc[4][4] = {};

    for (int kk = 0; kk < E; kk += 64) {
        if (zone == 3) {  // fp32 A: manual convert+write (swizzled slots)
            int srw = tid >> 3, cch = tid & 7;
            for (int c = 0; c < 4; ++c) {
                int row = c * 32 + srw;
                const float* ap = r + (size_t)(bm + row) * E + kk + cch * 8;
                float4 f0 = *(const float4*)ap;
                float4 f1 = *(const float4*)(ap + 4);
                bf16x8 v;
                v[0] = (bf16)f0.x; v[1] = (bf16)f0.y; v[2] = (bf16)f0.z; v[3] = (bf16)f0.w;
                v[4] = (bf16)f1.x; v[5] = (bf16)f1.y; v[6] = (bf16)f1.z; v[7] = (bf16)f1.w;
                *(bf16x8*)(As + row * 64 + ((cch ^ (row & 7)) << 3)) = v;
            }
        } else {
            for (int issue = 0; issue < 4; ++issue) {
                int q = (issue * 4 + wave) * 64 + lane;
                int row = q >> 3, cs = (q & 7) ^ ((q >> 3) & 7);
                int gm = bm + row;
                const bf16* ap;
                if (zone == 0) {
                    int b = gm >> 10;
                    ap = cat + ((size_t)(b * 2048 + 1024 + (gm & 1023))) * E;
                } else {
                    ap = cat + (size_t)gm * E;
                }
                ldg2lds16(ap + kk + cs * 8, As + (issue * 4 + wave) * 512);
            }
        }
        for (int issue = 0; issue < 4; ++issue) {
            int q = (issue * 4 + wave) * 64 + lane;
            int row = q >> 3, cs = (q & 7) ^ ((q >> 3) & 7);
            ldg2lds16(Bt + (size_t)(bn + row) * E + kk + cs * 8,
                      Bs + (issue * 4 + wave) * 512);
        }
        __syncthreads();
        for (int ks = 0; ks < 64; ks += 32) {
            bf16x8 af[4], bfr[4];
            for (int mt = 0; mt < 4; ++mt)
                af[mt] = frag8(As, wm + mt * 16 + l16, (ks >> 3) + quad);
            for (int nt = 0; nt < 4; ++nt)
                bfr[nt] = frag8(Bs, wn + nt * 16 + l16, (ks >> 3) + quad);
            for (int mt = 0; mt < 4; ++mt)
                for (int nt = 0; nt < 4; ++nt)
                    acc[mt][nt] = MFMA16(af[mt], bfr[nt], acc[mt][nt]);
        }
        __syncthreads();
    }

    if (zone == 2) {
        // Vt[b][h][d][j]: per-wave 64x64 swizzled LDS transpose, then b128 stores.
        bf16* buf = ((wave < 2) ? As : Bs) + (wave & 1) * 4096;
        for (int mt = 0; mt < 4; ++mt)
            for (int nt = 0; nt < 4; ++nt)
                for (int rr = 0; rr < 4; ++rr) {
                    int lr = mt * 16 + quad * 4 + rr;  // local j
                    int lc = nt * 16 + l16;            // local d
                    buf[lr * 64 + (((lc >> 3) ^ (lr & 7)) << 3) + (lc & 7)] =
                        (bf16)acc[mt][nt][rr];
                }
        int h = (bn + wn) >> 6;
        int gmw = bm + wm;
        int b = gmw >> 11, jb = gmw & 2047;
        for (int dp = 0; dp < 8; ++dp) {
            int dl = dp * 8 + (lane >> 3);
            int jl = (lane & 7) * 8;
            bf16x8 tmp;
            for (int jj = 0; jj < 8; ++jj) {
                int rw = jl + jj;
                tmp[jj] = buf[rw * 64 + (((dl >> 3) ^ (rw & 7)) << 3) + (dl & 7)];
            }
            *(bf16x8*)(Vt + (((size_t)(b * NH + h) * DH + dl) * KLEN) + jb + jl) = tmp;
        }
        return;
    }

    for (int mt = 0; mt < 4; ++mt)
        for (int nt = 0; nt < 4; ++nt)
            for (int rr = 0; rr < 4; ++rr) {
                int row = bm + wm + mt * 16 + quad * 4 + rr;
                int col = bn + wn + nt * 16 + l16;
                float v = acc[mt][nt][rr];
                if (zone == 0) {
                    int b = row >> 10, i = row & 1023;
                    int h = col >> 6, d = col & 63;
                    size_t o = (((size_t)(b * NH + h) * QL) + i) * DH + d;
                    Qw[o] = (bf16)((v + rwb[col]) * QSCALE);  // 1/sqrt(E)*log2e
                    Qr[o] = (bf16)((v + rrb[col]) * QSCALE);
                } else if (zone == 1) {
                    int b = row >> 11, j = row & 2047;
                    int h = col >> 6, d = col & 63;
                    Kh[(((size_t)(b * NH + h) * KLEN) + j) * DH + d] = (bf16)v;
                } else {
                    int h = col >> 6, d = col & 63;
                    RRh[(((size_t)h * KLEN) + row) * DH + d] = (bf16)v;
                }
            }
}

// ---------------------------------------------------------------- attention
// R20: R18 schedule (verified) + XCD-local balanced decode.
// 512 blocks x 512 thr; 8-wave producer/consumer (S: softmax, O: PV).
// Decode: xcd=id&7 owns combos xcd*4..+3 (4 heads, ~4MB K/V/RR = L2-fit).
// v6=id>>3: cl=v6&3 (combo lane), qi=v6>>2; qt0 = qi<8 ? qi : 23-qi;
// qt = (cl&1) ? 15-qt0 : qt0. Bijective per (xcd,cl); co-resident pairs
// sum to 49 phases under BOTH (v6,v6+1) and (v6,v6+32) dispatch pairings.
// Phase p: stage K(p+1), RR(c+p+2), V(p); S: MFMA(p)+softmax -> UB[p&1];
// O: PV(p-1) from UB/Vs[(p-1)&1]. One barrier per phase.
// R28: logits carry log2e -> __builtin_amdgcn_exp2f = bare v_exp_f32.
__global__ __launch_bounds__(512, 4) void attn_k(
    const bf16* __restrict__ Qw, const bf16* __restrict__ Qr,
    const bf16* __restrict__ Kh, const bf16* __restrict__ Vt,
    const bf16* __restrict__ RRh, bf16* __restrict__ AttO) {
    __shared__ __align__(16) bf16 Ks[2][64 * 64];
    __shared__ __align__(16) bf16 Vs[2][64 * 64];
    __shared__ __align__(16) bf16 RRing[3][64 * 64];
    __shared__ __align__(16) bf16 UB[2][4][16 * 88];  // P dbuf (+linv stash)

    const int tid = threadIdx.x;
    const int wave = tid >> 6, lane = tid & 63, quad = lane >> 4, l16 = lane & 15;
    const int id = blockIdx.x;
    // XCD-aware decode (hw xcd = blockIdx % 8 round-robin; perf-only).
    const int xcd = id & 7;
    const int v6 = id >> 3;       // 0..63 within XCD
    const int cl = v6 & 3;        // combo lane
    const int qi = v6 >> 2;       // 0..15
    const int qt0 = (qi < 8) ? qi : 23 - qi;
    const int qt = (cl & 1) ? 15 - qt0 : qt0;
    const int combo = xcd * 4 + cl;  // 0..31 = (b,h)
    const int b = combo >> 4, h = combo & 15;
    const int i0 = qt * 64;
    const bool isS = wave < 4;
    const int sw = isS ? wave : wave - 4;  // q-row group 0..3 within block

    const bf16* Qwb = Qw + ((size_t)(b * NH + h) * QL) * DH;
    const bf16* Qrb = Qr + ((size_t)(b * NH + h) * QL) * DH;
    const bf16* Kb = Kh + ((size_t)(b * NH + h) * KLEN) * DH;
    const bf16* Vb = Vt + ((size_t)(b * NH + h) * DH) * KLEN;  // [d][j]
    const bf16* Rb = RRh + ((size_t)h * KLEN) * DH;

    bf16x8 qw0, qw1, qr0, qr1;
    if (isS) {
        int i = i0 + sw * 16 + l16;
        qw0 = *(const bf16x8*)(Qwb + (size_t)i * DH + quad * 8);
        qw1 = *(const bf16x8*)(Qwb + (size_t)i * DH + 32 + quad * 8);
        qr0 = *(const bf16x8*)(Qrb + (size_t)i * DH + quad * 8);
        qr1 = *(const bf16x8*)(Qrb + (size_t)i * DH + 32 + quad * 8);
    }

    float lpart[4] = {0.f, 0.f, 0.f, 0.f};
    f32x4 oacc[4] = {};

    const int ntiles = qt + 17;
    const int cbase = 15 - qt;  // global RR chunk of window start at t=0
    const int ptbase = 3 - sw;

    // per-wave 512-element (1KB) DMA slices; all 8 waves participate.
    auto stageK = [&](int t) {
        int q = wave * 64 + lane;
        int row = q >> 3, cs = (q & 7) ^ (row & 7);
        ldg2lds16(Kb + (size_t)(t * 64 + row) * DH + cs * 8,
                  Ks[t & 1] + wave * 512);
    };
    auto stageV = [&](int t) {
        int q = wave * 64 + lane;
        int row = q >> 3, cs = (q & 7) ^ (row & 7);
        ldg2lds16(Vb + (size_t)row * KLEN + t * 64 + cs * 8,
                  Vs[t & 1] + wave * 512);
    };
    auto stageRR = [&](int c) {
        int q = wave * 64 + lane;
        int row = q >> 3, cs = (q & 7) ^ (row & 7);
        int pr = c * 64 + row;
        pr = pr > KLEN - 1 ? KLEN - 1 : pr;  // clamped rows feed masked cols
        ldg2lds16(Rb + (size_t)pr * DH + cs * 8, RRing[c % 3] + wave * 512);
    };

    stageK(0);
    stageRR(cbase);
    stageRR(cbase + 1);
    __syncthreads();

    for (int p = 0; p <= ntiles; ++p) {
        if (p + 1 < ntiles) {
            stageK(p + 1);
            stageRR(cbase + p + 2);
        }
        if (p < ntiles) stageV(p);

        if (isS) {
            __builtin_amdgcn_s_setprio(1);
            if (p < ntiles) {
                const bf16* Kt = Ks[p & 1];
                const bf16* Rlo = RRing[(cbase + p) % 3];
                const bf16* Rhi = RRing[(cbase + p + 1) % 3];

                // BD = Qr @ RRwindow^T (this wave's 5 pt tiles) -> registers
                f32x4 bacc[5];
                for (int pi = 0; pi < 5; ++pi) {
                    int pt = ptbase + pi;
                    const bf16* Rsrc = (pt < 4) ? Rlo : Rhi;
                    int rrow = (pt & 3) * 16 + l16;
                    f32x4 a = {};
                    a = MFMA16(qr0, frag8(Rsrc, rrow, quad), a);
                    a = MFMA16(qr1, frag8(Rsrc, rrow, 4 + quad), a);
                    bacc[pi] = a;
                }

                // AC = Qw @ K^T
                f32x4 sacc[4];
                for (int nt = 0; nt < 4; ++nt) {
                    f32x4 a = {};
                    a = MFMA16(qw0, frag8(Kt, nt * 16 + l16, quad), a);
                    a = MFMA16(qw1, frag8(Kt, nt * 16 + l16, 4 + quad), a);
                    sacc[nt] = a;
                }

                // p = exp2(AC+BD) (log2e folded upstream); BD rel-shift gather.
                float sv[4][4];
                const bool lastt = (p == ntiles - 1);
                for (int rr = 0; rr < 4; ++rr) {
                    const int lr = quad * 4 + rr;
                    const int srcl = quad * 16 + ((l16 - lr - 1) & 15);
                    float g[5];
                    for (int pi = 0; pi < 5; ++pi) g[pi] = __shfl(bacc[pi][rr], srcl);
                    const bool hi = (l16 > lr);
                    for (int nt = 0; nt < 4; ++nt) {
                        float bdv = hi ? g[nt + 1] : g[nt];
                        float pv = __builtin_amdgcn_exp2f(sacc[nt][rr] + bdv);
                        if (lastt) {
                            int i = i0 + sw * 16 + lr;
                            int j = p * 64 + nt * 16 + l16;
                            if (j > i + ML) pv = 0.f;
                        }
                        sv[nt][rr] = pv;
                        lpart[rr] += pv;
                    }
                }

                // P: C-layout -> UB[p&1] (A-layout source for O-waves)
                bf16* UBd = UB[p & 1][sw];
                for (int nt = 0; nt < 4; ++nt)
                    for (int rr = 0; rr < 4; ++rr)
                        UBd[(quad * 4 + rr) * 88 + nt * 16 + l16] = (bf16)sv[nt][rr];
            } else {
                // final phase: deferred l reduction -> linv stash in dead UB half
                float* lp = (float*)(&UB[ntiles & 1][sw][0]);
                for (int rr = 0; rr < 4; ++rr) {
                    float v = lpart[rr];
                    v += __shfl_xor(v, 1);
                    v += __shfl_xor(v, 2);
                    v += __shfl_xor(v, 4);
                    v += __shfl_xor(v, 8);
                    lp[lane * 4 + rr] = 1.f / v;
                }
            }
            __builtin_amdgcn_s_setprio(0);
        } else if (p >= 1) {
            // O-waves: PV for tile p-1
            const bf16* Vl = Vs[(p - 1) & 1];
            const bf16* UBs = UB[(p - 1) & 1][sw];
            for (int c = 0; c < 2; ++c) {
                bf16x8 pa = *(const bf16x8*)(&UBs[l16 * 88 + c * 32 + quad * 8]);
                for (int nt = 0; nt < 4; ++nt) {
                    bf16x8 vb = frag8(Vl, nt * 16 + l16, c * 4 + quad);
                    oacc[nt] = MFMA16(pa, vb, oacc[nt]);
                }
            }
        }
        __syncthreads();  // DMA drain + UB handoff + buffer WAR
    }

    if (!isS) {
        const float* lp = (const float*)(&UB[ntiles & 1][sw][0]);
        for (int nt = 0; nt < 4; ++nt)
            for (int rr = 0; rr < 4; ++rr) {
                int i = i0 + sw * 16 + quad * 4 + rr;
                int d = nt * 16 + l16;
                AttO[((size_t)(b * QL + i)) * E + h * DH + d] =
                    (bf16)(oacc[nt][rr] * lp[lane * 4 + rr]);
            }
    }
}

// ---------------------------------------------------------------- out proj
// R18: split-K x4. 512 blocks -> 2 blocks/CU. z in 0..3 computes K-slice
// z*256..+256 -> partial Xp[z] (fp32); z==3 partial over dead WqT..WrT.
__global__ __launch_bounds__(256) void gemm_o(
    const bf16* __restrict__ A, const bf16* __restrict__ Bt,
    float* __restrict__ Xp, float* __restrict__ Xp3) {
    __shared__ __align__(16) bf16 As[128 * 64];
    __shared__ __align__(16) bf16 Bs[128 * 64];
    const int tid = threadIdx.x;
    const int wave = tid >> 6, lane = tid & 63, quad = lane >> 4, l16 = lane & 15;
    const int bm = blockIdx.y * 128, bn = blockIdx.x * 128;
    const int kbase = blockIdx.z * 256;
    const int wm = (wave >> 1) * 64, wn = (wave & 1) * 64;

    f32x4 acc[4][4] = {};

    for (int s = 0; s < 4; ++s) {
        const int kk = kbase + s * 64;
        for (int issue = 0; issue < 4; ++issue) {
            int q = (issue * 4 + wave) * 64 + lane;
            int row = q >> 3, cs = (q & 7) ^ ((q >> 3) & 7);
            ldg2lds16(A + (size_t)(bm + row) * E + kk + cs * 8,
                      As + (issue * 4 + wave) * 512);
            ldg2lds16(Bt + (size_t)(bn + row) * E + kk + cs * 8,
                      Bs + (issue * 4 + wave) * 512);
        }
        __syncthreads();
        for (int ks = 0; ks < 64; ks += 32) {
            bf16x8 af[4], bfr[4];
            for (int mt = 0; mt < 4; ++mt)
                af[mt] = frag8(As, wm + mt * 16 + l16, (ks >> 3) + quad);
            for (int nt = 0; nt < 4; ++nt)
                bfr[nt] = frag8(Bs, wn + nt * 16 + l16, (ks >> 3) + quad);
            for (int mt = 0; mt < 4; ++mt)
                for (int nt = 0; nt < 4; ++nt)
                    acc[mt][nt] = MFMA16(af[mt], bfr[nt], acc[mt][nt]);
        }
        __syncthreads();
    }

    float* Xz = (blockIdx.z == 3) ? Xp3
                                  : Xp + (size_t)blockIdx.z * 2048 * 1024;
    for (int mt = 0; mt < 4; ++mt)
        for (int nt = 0; nt < 4; ++nt)
            for (int rr = 0; rr < 4; ++rr) {
                int row = bm + wm + mt * 16 + quad * 4 + rr;
                int col = bn + wn + nt * 16 + l16;
                Xz[(size_t)row * E + col] = acc[mt][nt][rr];
            }
}

// ---------------------------------------------------------------- layernorm
// x = Xp0 + Xp1 + Xp2 + Xp3 + resid(w); out = LN(x)*gamma+beta
// R24: 512 blocks x 4 rows (per-row math identical to R23; float4 path).
__global__ __launch_bounds__(256) void ln_k(const float* __restrict__ Xp,
                                            const float* __restrict__ Xp3,
                                            const float* __restrict__ resid,
                                            const float* __restrict__ gamma,
                                            const float* __restrict__ beta,
                                            float* __restrict__ out) {
    const int tid = threadIdx.x;
    __shared__ float rs[4], rq[4];
    const int wave = tid >> 6, lane = tid & 63;
    float4 g = ((const float4*)gamma)[tid];
    float4 bt = ((const float4*)beta)[tid];
    for (int it = 0; it < 4; ++it) {
        const int row = blockIdx.x * 4 + it;
        const float4* x0 = (const float4*)(Xp + (size_t)row * E);
        const float4* x1 = (const float4*)(Xp + (size_t)2048 * 1024 + (size_t)row * E);
        const float4* x2 = (const float4*)(Xp + (size_t)2 * 2048 * 1024 + (size_t)row * E);
        const float4* x3 = (const float4*)(Xp3 + (size_t)row * E);
        const float4* xr = (const float4*)(resid + (size_t)row * E);
        float4 a0 = x0[tid], a1 = x1[tid], a2 = x2[tid], a3 = x3[tid], ar = xr[tid];
        float4 v;
        v.x = a0.x + a1.x + a2.x + a3.x + ar.x;
        v.y = a0.y + a1.y + a2.y + a3.y + ar.y;
        v.z = a0.z + a1.z + a2.z + a3.z + ar.z;
        v.w = a0.w + a1.w + a2.w + a3.w + ar.w;
        float s = v.x + v.y + v.z + v.w;
        float q = v.x * v.x + v.y * v.y + v.z * v.z + v.w * v.w;
        for (int off = 32; off > 0; off >>= 1) {
            s += __shfl_down(s, off);
            q += __shfl_down(q, off);
        }
        if (lane == 0) { rs[wave] = s; rq[wave] = q; }
        __syncthreads();
        float S = rs[0] + rs[1] + rs[2] + rs[3];
        float Q = rq[0] + rq[1] + rq[2] + rq[3];
        float mean = S * (1.f / E);
        float var = fmaxf(Q * (1.f / E) - mean * mean, 0.f);
        float rstd = rsqrtf(var + 1e-3f);
        float4 o;
        o.x = (v.x - mean) * rstd * g.x + bt.x;
        o.y = (v.y - mean) * rstd * g.y + bt.y;
        o.z = (v.z - mean) * rstd * g.z + bt.z;
        o.w = (v.w - mean) * rstd * g.w + bt.w;
        ((float4*)(out + (size_t)row * E))[tid] = o;
        __syncthreads();  // rs/rq reuse across rows
    }
}

// ---------------------------------------------------------------- launch
extern "C" void kernel_launch(void* const* d_in, const int* in_sizes, int n_in,
                              void* d_out, int out_size, void* d_ws,
                              size_t ws_size, hipStream_t stream) {
    (void)in_sizes; (void)n_in; (void)out_size; (void)ws_size;
    const float* w = (const float*)d_in[0];
    const float* r = (const float*)d_in[1];
    const float* rwb = (const float*)d_in[3];
    const float* rrb = (const float*)d_in[4];
    const float* member = (const float*)d_in[5];
    const float* Wq = (const float*)d_in[6];
    const float* Wk = (const float*)d_in[7];
    const float* Wv = (const float*)d_in[8];
    const float* Wr = (const float*)d_in[9];
    const float* Wo = (const float*)d_in[10];
    const float* gamma = (const float*)d_in[11];
    const float* beta = (const float*)d_in[12];
    float* out = (float*)d_out;

    char* ws = (char*)d_ws;
    const size_t MB = 1024 * 1024;
    bf16* WqT = (bf16*)(ws + 0 * MB);   // 0-8: WqT..WrT (dead after proj_k;
    bf16* WkT = (bf16*)(ws + 2 * MB);   //   reused as Xp3 by gemm_o)
    bf16* WvT = (bf16*)(ws + 4 * MB);
    bf16* WrT = (bf16*)(ws + 6 * MB);
    bf16* WoT = (bf16*)(ws + 8 * MB);   // live until gemm_o
    bf16* cat = (bf16*)(ws + 10 * MB);  // 10-18; dead after proj_k
    bf16* AttO = (bf16*)(ws + 14 * MB); // 14-18 (over cat 2nd half)
    bf16* Qw = (bf16*)(ws + 18 * MB);
    bf16* Qr = (bf16*)(ws + 22 * MB);
    float* Xp = (float*)(ws + 18 * MB); // 18-42: Xp z=0..2 (over Qw/Qr/Kh,
    bf16* Kh = (bf16*)(ws + 26 * MB);   //   dead after attn)
    bf16* Vt = (bf16*)(ws + 34 * MB);   // Vt dead after attn -> Xp z=2
    bf16* RRh = (bf16*)(ws + 42 * MB);
    float* Xp3 = (float*)(ws + 0 * MB); // z=3 partial over WqT..WrT
    // high-water: 46 MB (unchanged)

    pre_k<<<1792, 256, 0, stream>>>(Wq, Wk, Wv, Wr, Wo, member, w, WqT, WkT,
                                    WvT, WrT, WoT, cat);

    proj_k<<<768, 256, 0, stream>>>(cat, r, WqT, WkT, WvT, WrT, rwb, rrb, Qw,
                                    Qr, Kh, Vt, RRh);

    attn_k<<<512, 512, 0, stream>>>(Qw, Qr, Kh, Vt, RRh, AttO);

    gemm_o<<<dim3(8, 16, 4), 256, 0, stream>>>(AttO, WoT, Xp, Xp3);
    ln_k<<<512, 256, 0, stream>>>(Xp, Xp3, w, gamma, beta, out);
}

// Round 15
// 225.102 us; speedup vs baseline: 1.0924x; 1.0515x over previous
//
#include <hip/hip_runtime.h>

// Transformer-XL relative multi-head attention + LayerNorm.
// Inputs/outputs fp32; internal MFMA compute in bf16.
// B=2, H=16, D=64, E=1024, QL=1024, ML=1024, KLEN=2048.
// rel_shift identity: unmasked (j<=i+ML): BDshift[i,j] = BD[i, j-i+QL-1].
// R30: proj_k A-local XCD remap (decode-only; frozen body untouched).
//   R28/R29 CONFIRMED: attn 62.5us w/ QSCALE fold + bare v_exp (total
//   236.7 best). R23's remap rejection had WRONG arithmetic: A (8MB) is
//   4x B (2MB) per zone — broadcast the SMALLER operand. Current decode
//   is B-local (xcd owns bn col, streams ALL A: ~8A+B L2 traffic/zone);
//   new decode is A-local (xcd owns contiguous bm slice: A+8B).
//   zones 1/2: bm=(lid&7)*4+((lid>>3)&3), bn=lid>>5 (bijective);
//   zones 0/3: bm=(lid&7)*2+((lid>>3)&1), bn=lid>>4.
//   Mechanism: proj is drain-latency-bound; L2-hit (~200cy) vs HBM
//   (~900cy) shortens barrier-drain tails. Bit-identical output.
// R28: QSCALE fold + __builtin_amdgcn_exp2f (exp2f was precise libm!).
// R26: proj_k zone order z3,z0,z1,z2 (heavy-first tail trim, -4us).
// R22: proj_k body FROZEN at R9 (R14/R19/R21 regressed).
// R20: attn_k XCD-local balanced decode (FETCH 93->16MB).
// R18: setprio on S-compute; gemm_o split-K x4.
// R17: 8-wave producer/consumer attn (S: softmax -> UB dbuf; O: PV).

typedef __bf16 bf16;
typedef __bf16 bf16x4 __attribute__((ext_vector_type(4)));
typedef __bf16 bf16x8 __attribute__((ext_vector_type(8)));
typedef float f32x4 __attribute__((ext_vector_type(4)));

#define MFMA16(a, b, c) __builtin_amdgcn_mfma_f32_16x16x32_bf16((a), (b), (c), 0, 0, 0)

constexpr int E = 1024;
constexpr int NH = 16;
constexpr int DH = 64;
constexpr int QL = 1024;
constexpr int ML = 1024;
constexpr int KLEN = 2048;
// 1/sqrt(E) * log2(e): attn computes exp2(scaled logits) = exp(logits/32)
constexpr float QSCALE = 0.03125f * 1.44269504088896340736f;

// async 16B global->LDS. LDS dest is wave-uniform base + lane*16.
__device__ __forceinline__ void ldg2lds16(const bf16* g, bf16* l) {
    __builtin_amdgcn_global_load_lds(
        (const __attribute__((address_space(1))) unsigned int*)g,
        (__attribute__((address_space(3))) unsigned int*)l, 16, 0, 0);
}

// read a b128 fragment from an unpadded 64-col swizzled tile.
// physical 16B-chunk = logical chunk ^ (row & 7).
__device__ __forceinline__ bf16x8 frag8(const bf16* t, int row, int ch) {
    return *(const bf16x8*)(t + row * 64 + ((ch ^ (row & 7)) << 3));
}

// ---------------------------------------------------------------- pre
// R24: blocks 0..1279: 5 weight transposes, 64x64 tiles
//   (WT[n][k] = bf16(W[k][n]) — exact copy, bit-identical any tiling).
// blocks 1280..1791: cat, 8 rows per block.
__global__ void pre_k(const float* __restrict__ Wq, const float* __restrict__ Wk,
                      const float* __restrict__ Wv, const float* __restrict__ Wr,
                      const float* __restrict__ Wo, const float* __restrict__ member,
                      const float* __restrict__ w, bf16* __restrict__ WqT,
                      bf16* __restrict__ WkT, bf16* __restrict__ WvT,
                      bf16* __restrict__ WrT, bf16* __restrict__ WoT,
                      bf16* __restrict__ cat) {
    const int id = blockIdx.x;
    const int tid = threadIdx.x;
    __shared__ float t[64][65];
    if (id < 1280) {
        const float* W; bf16* WT;
        switch (id >> 8) {
            case 0: W = Wq; WT = WqT; break;
            case 1: W = Wk; WT = WkT; break;
            case 2: W = Wv; WT = WvT; break;
            case 3: W = Wr; WT = WrT; break;
            default: W = Wo; WT = WoT; break;
        }
        int xy = id & 255;                       // 16x16 tiles of 64x64
        int bx = (xy & 15) * 64, by = (xy >> 4) * 64;
        int x4 = (tid & 15) * 4, yy = tid >> 4;  // 16 col-quads x 16 rows
        for (int ry = 0; ry < 4; ++ry) {
            int row = ry * 16 + yy;
            float4 f = *(const float4*)(W + (size_t)(by + row) * E + bx + x4);
            t[row][x4 + 0] = f.x; t[row][x4 + 1] = f.y;
            t[row][x4 + 2] = f.z; t[row][x4 + 3] = f.w;
        }
        __syncthreads();
        for (int ry = 0; ry < 4; ++ry) {
            int r = ry * 16 + yy;
            bf16x4 o;
            o[0] = (bf16)t[x4 + 0][r]; o[1] = (bf16)t[x4 + 1][r];
            o[2] = (bf16)t[x4 + 2][r]; o[3] = (bf16)t[x4 + 3][r];
            *(bf16x4*)(WT + (size_t)(bx + r) * E + by + x4) = o;
        }
    } else {
        int row0 = (id - 1280) * 8;
        for (int rr = 0; rr < 8; ++rr) {
            int row = row0 + rr;
            int b = row >> 11, jj = row & 2047;
            const float* src = (jj < ML) ? member + ((size_t)(b * ML + jj)) * E
                                         : w + ((size_t)(b * QL + (jj - ML))) * E;
            float4 f = *(const float4*)(src + tid * 4);
            bf16x4 o;
            o[0] = (bf16)f.x; o[1] = (bf16)f.y; o[2] = (bf16)f.z; o[3] = (bf16)f.w;
            *(bf16x4*)(cat + (size_t)row * E + tid * 4) = o;
        }
    }
}

// ---------------------------------------------------------------- projections
// EXACT R9 body (FROZEN). Single-buffer two-barrier staging.
// R26 decode: heavy zones first. id<128: zone3 (R->RRh); 128..255: zone0
// (Q->Qw/Qr); 256..511: zone1 (K->Kh); 512..767: zone2 (V->Vt).
// R30 A-local remap: xcd (=lid%8, since all zone bases are %8==0) owns a
// contiguous bm slice; bn iterates within XCD (B-panel switches every
// 2/4 blocks, A-slice L2-resident across all bn). Bijective relabel.
// R27: zone-0 scale folds log2e (QSCALE) so attn can use raw exp2.
__global__ __launch_bounds__(256) void proj_k(
    const bf16* __restrict__ cat, const float* __restrict__ r,
    const bf16* __restrict__ WqT, const bf16* __restrict__ WkT,
    const bf16* __restrict__ WvT, const bf16* __restrict__ WrT,
    const float* __restrict__ rwb, const float* __restrict__ rrb,
    bf16* __restrict__ Qw, bf16* __restrict__ Qr, bf16* __restrict__ Kh,
    bf16* __restrict__ Vt, bf16* __restrict__ RRh) {
    __shared__ __align__(16) bf16 As[128 * 64];
    __shared__ __align__(16) bf16 Bs[128 * 64];
    const int tid = threadIdx.x;
    const int wave = tid >> 6, lane = tid & 63, quad = lane >> 4, l16 = lane & 15;

    int id = blockIdx.x, zone, base;
    if (id < 128) { zone = 3; base = 0; }
    else if (id < 256) { zone = 0; base = 128; }
    else if (id < 512) { zone = 1; base = 256; }
    else { zone = 2; base = 512; }
    const int lid = id - base;
    int bm, bn;
    if (zone == 1 || zone == 2) {  // 256 blocks: 32 bm x 8 bn
        bm = ((lid & 7) * 4 + ((lid >> 3) & 3)) * 128;
        bn = (lid >> 5) * 128;
    } else {                       // 128 blocks: 16 bm x 8 bn
        bm = ((lid & 7) * 2 + ((lid >> 3) & 1)) * 128;
        bn = (lid >> 4) * 128;
    }
    const bf16* Bt = (zone == 0) ? WqT : (zone == 1) ? WkT : (zone == 2) ? WvT : WrT;
    const int wm = (wave >> 1) * 64, wn = (wave & 1) * 64;

    f32x4 acc[4][4] = {};

    for (int kk = 0; kk < E; kk += 64) {
        if (zone == 3) {  // fp32 A: manual convert+write (swizzled slots)
            int srw = tid >> 3, cch = tid & 7;
            for (int c = 0; c < 4; ++c) {
                int row = c * 32 + srw;
                const float* ap = r + (size_t)(bm + row) * E + kk + cch * 8;
                float4 f0 = *(const float4*)ap;
                float4 f1 = *(const float4*)(ap + 4);
                bf16x8 v;
                v[0] = (bf16)f0.x; v[1] = (bf16)f0.y; v[2] = (bf16)f0.z; v[3] = (bf16)f0.w;
                v[4] = (bf16)f1.x; v[5] = (bf16)f1.y; v[6] = (bf16)f1.z; v[7] = (bf16)f1.w;
                *(bf16x8*)(As + row * 64 + ((cch ^ (row & 7)) << 3)) = v;
            }
        } else {
            for (int issue = 0; issue < 4; ++issue) {
                int q = (issue * 4 + wave) * 64 + lane;
                int row = q >> 3, cs = (q & 7) ^ ((q >> 3) & 7);
                int gm = bm + row;
                const bf16* ap;
                if (zone == 0) {
                    int b = gm >> 10;
                    ap = cat + ((size_t)(b * 2048 + 1024 + (gm & 1023))) * E;
                } else {
                    ap = cat + (size_t)gm * E;
                }
                ldg2lds16(ap + kk + cs * 8, As + (issue * 4 + wave) * 512);
            }
        }
        for (int issue = 0; issue < 4; ++issue) {
            int q = (issue * 4 + wave) * 64 + lane;
            int row = q >> 3, cs = (q & 7) ^ ((q >> 3) & 7);
            ldg2lds16(Bt + (size_t)(bn + row) * E + kk + cs * 8,
                      Bs + (issue * 4 + wave) * 512);
        }
        __syncthreads();
        for (int ks = 0; ks < 64; ks += 32) {
            bf16x8 af[4], bfr[4];
            for (int mt = 0; mt < 4; ++mt)
                af[mt] = frag8(As, wm + mt * 16 + l16, (ks >> 3) + quad);
            for (int nt = 0; nt < 4; ++nt)
                bfr[nt] = frag8(Bs, wn + nt * 16 + l16, (ks >> 3) + quad);
            for (int mt = 0; mt < 4; ++mt)
                for (int nt = 0; nt < 4; ++nt)
                    acc[mt][nt] = MFMA16(af[mt], bfr[nt], acc[mt][nt]);
        }
        __syncthreads();
    }

    if (zone == 2) {
        // Vt[b][h][d][j]: per-wave 64x64 swizzled LDS transpose, then b128 stores.
        bf16* buf = ((wave < 2) ? As : Bs) + (wave & 1) * 4096;
        for (int mt = 0; mt < 4; ++mt)
            for (int nt = 0; nt < 4; ++nt)
                for (int rr = 0; rr < 4; ++rr) {
                    int lr = mt * 16 + quad * 4 + rr;  // local j
                    int lc = nt * 16 + l16;            // local d
                    buf[lr * 64 + (((lc >> 3) ^ (lr & 7)) << 3) + (lc & 7)] =
                        (bf16)acc[mt][nt][rr];
                }
        int h = (bn + wn) >> 6;
        int gmw = bm + wm;
        int b = gmw >> 11, jb = gmw & 2047;
        for (int dp = 0; dp < 8; ++dp) {
            int dl = dp * 8 + (lane >> 3);
            int jl = (lane & 7) * 8;
            bf16x8 tmp;
            for (int jj = 0; jj < 8; ++jj) {
                int rw = jl + jj;
                tmp[jj] = buf[rw * 64 + (((dl >> 3) ^ (rw & 7)) << 3) + (dl & 7)];
            }
            *(bf16x8*)(Vt + (((size_t)(b * NH + h) * DH + dl) * KLEN) + jb + jl) = tmp;
        }
        return;
    }

    for (int mt = 0; mt < 4; ++mt)
        for (int nt = 0; nt < 4; ++nt)
            for (int rr = 0; rr < 4; ++rr) {
                int row = bm + wm + mt * 16 + quad * 4 + rr;
                int col = bn + wn + nt * 16 + l16;
                float v = acc[mt][nt][rr];
                if (zone == 0) {
                    int b = row >> 10, i = row & 1023;
                    int h = col >> 6, d = col & 63;
                    size_t o = (((size_t)(b * NH + h) * QL) + i) * DH + d;
                    Qw[o] = (bf16)((v + rwb[col]) * QSCALE);  // 1/sqrt(E)*log2e
                    Qr[o] = (bf16)((v + rrb[col]) * QSCALE);
                } else if (zone == 1) {
                    int b = row >> 11, j = row & 2047;
                    int h = col >> 6, d = col & 63;
                    Kh[(((size_t)(b * NH + h) * KLEN) + j) * DH + d] = (bf16)v;
                } else {
                    int h = col >> 6, d = col & 63;
                    RRh[(((size_t)h * KLEN) + row) * DH + d] = (bf16)v;
                }
            }
}

// ---------------------------------------------------------------- attention
// R20: R18 schedule (verified) + XCD-local balanced decode.
// 512 blocks x 512 thr; 8-wave producer/consumer (S: softmax, O: PV).
// Decode: xcd=id&7 owns combos xcd*4..+3 (4 heads, ~4MB K/V/RR = L2-fit).
// v6=id>>3: cl=v6&3 (combo lane), qi=v6>>2; qt0 = qi<8 ? qi : 23-qi;
// qt = (cl&1) ? 15-qt0 : qt0. Bijective per (xcd,cl); co-resident pairs
// sum to 49 phases under BOTH (v6,v6+1) and (v6,v6+32) dispatch pairings.
// Phase p: stage K(p+1), RR(c+p+2), V(p); S: MFMA(p)+softmax -> UB[p&1];
// O: PV(p-1) from UB/Vs[(p-1)&1]. One barrier per phase.
// R28: logits carry log2e -> __builtin_amdgcn_exp2f = bare v_exp_f32.
__global__ __launch_bounds__(512, 4) void attn_k(
    const bf16* __restrict__ Qw, const bf16* __restrict__ Qr,
    const bf16* __restrict__ Kh, const bf16* __restrict__ Vt,
    const bf16* __restrict__ RRh, bf16* __restrict__ AttO) {
    __shared__ __align__(16) bf16 Ks[2][64 * 64];
    __shared__ __align__(16) bf16 Vs[2][64 * 64];
    __shared__ __align__(16) bf16 RRing[3][64 * 64];
    __shared__ __align__(16) bf16 UB[2][4][16 * 88];  // P dbuf (+linv stash)

    const int tid = threadIdx.x;
    const int wave = tid >> 6, lane = tid & 63, quad = lane >> 4, l16 = lane & 15;
    const int id = blockIdx.x;
    // XCD-aware decode (hw xcd = blockIdx % 8 round-robin; perf-only).
    const int xcd = id & 7;
    const int v6 = id >> 3;       // 0..63 within XCD
    const int cl = v6 & 3;        // combo lane
    const int qi = v6 >> 2;       // 0..15
    const int qt0 = (qi < 8) ? qi : 23 - qi;
    const int qt = (cl & 1) ? 15 - qt0 : qt0;
    const int combo = xcd * 4 + cl;  // 0..31 = (b,h)
    const int b = combo >> 4, h = combo & 15;
    const int i0 = qt * 64;
    const bool isS = wave < 4;
    const int sw = isS ? wave : wave - 4;  // q-row group 0..3 within block

    const bf16* Qwb = Qw + ((size_t)(b * NH + h) * QL) * DH;
    const bf16* Qrb = Qr + ((size_t)(b * NH + h) * QL) * DH;
    const bf16* Kb = Kh + ((size_t)(b * NH + h) * KLEN) * DH;
    const bf16* Vb = Vt + ((size_t)(b * NH + h) * DH) * KLEN;  // [d][j]
    const bf16* Rb = RRh + ((size_t)h * KLEN) * DH;

    bf16x8 qw0, qw1, qr0, qr1;
    if (isS) {
        int i = i0 + sw * 16 + l16;
        qw0 = *(const bf16x8*)(Qwb + (size_t)i * DH + quad * 8);
        qw1 = *(const bf16x8*)(Qwb + (size_t)i * DH + 32 + quad * 8);
        qr0 = *(const bf16x8*)(Qrb + (size_t)i * DH + quad * 8);
        qr1 = *(const bf16x8*)(Qrb + (size_t)i * DH + 32 + quad * 8);
    }

    float lpart[4] = {0.f, 0.f, 0.f, 0.f};
    f32x4 oacc[4] = {};

    const int ntiles = qt + 17;
    const int cbase = 15 - qt;  // global RR chunk of window start at t=0
    const int ptbase = 3 - sw;

    // per-wave 512-element (1KB) DMA slices; all 8 waves participate.
    auto stageK = [&](int t) {
        int q = wave * 64 + lane;
        int row = q >> 3, cs = (q & 7) ^ (row & 7);
        ldg2lds16(Kb + (size_t)(t * 64 + row) * DH + cs * 8,
                  Ks[t & 1] + wave * 512);
    };
    auto stageV = [&](int t) {
        int q = wave * 64 + lane;
        int row = q >> 3, cs = (q & 7) ^ (row & 7);
        ldg2lds16(Vb + (size_t)row * KLEN + t * 64 + cs * 8,
                  Vs[t & 1] + wave * 512);
    };
    auto stageRR = [&](int c) {
        int q = wave * 64 + lane;
        int row = q >> 3, cs = (q & 7) ^ (row & 7);
        int pr = c * 64 + row;
        pr = pr > KLEN - 1 ? KLEN - 1 : pr;  // clamped rows feed masked cols
        ldg2lds16(Rb + (size_t)pr * DH + cs * 8, RRing[c % 3] + wave * 512);
    };

    stageK(0);
    stageRR(cbase);
    stageRR(cbase + 1);
    __syncthreads();

    for (int p = 0; p <= ntiles; ++p) {
        if (p + 1 < ntiles) {
            stageK(p + 1);
            stageRR(cbase + p + 2);
        }
        if (p < ntiles) stageV(p);

        if (isS) {
            __builtin_amdgcn_s_setprio(1);
            if (p < ntiles) {
                const bf16* Kt = Ks[p & 1];
                const bf16* Rlo = RRing[(cbase + p) % 3];
                const bf16* Rhi = RRing[(cbase + p + 1) % 3];

                // BD = Qr @ RRwindow^T (this wave's 5 pt tiles) -> registers
                f32x4 bacc[5];
                for (int pi = 0; pi < 5; ++pi) {
                    int pt = ptbase + pi;
                    const bf16* Rsrc = (pt < 4) ? Rlo : Rhi;
                    int rrow = (pt & 3) * 16 + l16;
                    f32x4 a = {};
                    a = MFMA16(qr0, frag8(Rsrc, rrow, quad), a);
                    a = MFMA16(qr1, frag8(Rsrc, rrow, 4 + quad), a);
                    bacc[pi] = a;
                }

                // AC = Qw @ K^T
                f32x4 sacc[4];
                for (int nt = 0; nt < 4; ++nt) {
                    f32x4 a = {};
                    a = MFMA16(qw0, frag8(Kt, nt * 16 + l16, quad), a);
                    a = MFMA16(qw1, frag8(Kt, nt * 16 + l16, 4 + quad), a);
                    sacc[nt] = a;
                }

                // p = exp2(AC+BD) (log2e folded upstream); BD rel-shift gather.
                float sv[4][4];
                const bool lastt = (p == ntiles - 1);
                for (int rr = 0; rr < 4; ++rr) {
                    const int lr = quad * 4 + rr;
                    const int srcl = quad * 16 + ((l16 - lr - 1) & 15);
                    float g[5];
                    for (int pi = 0; pi < 5; ++pi) g[pi] = __shfl(bacc[pi][rr], srcl);
                    const bool hi = (l16 > lr);
                    for (int nt = 0; nt < 4; ++nt) {
                        float bdv = hi ? g[nt + 1] : g[nt];
                        float pv = __builtin_amdgcn_exp2f(sacc[nt][rr] + bdv);
                        if (lastt) {
                            int i = i0 + sw * 16 + lr;
                            int j = p * 64 + nt * 16 + l16;
                            if (j > i + ML) pv = 0.f;
                        }
                        sv[nt][rr] = pv;
                        lpart[rr] += pv;
                    }
                }

                // P: C-layout -> UB[p&1] (A-layout source for O-waves)
                bf16* UBd = UB[p & 1][sw];
                for (int nt = 0; nt < 4; ++nt)
                    for (int rr = 0; rr < 4; ++rr)
                        UBd[(quad * 4 + rr) * 88 + nt * 16 + l16] = (bf16)sv[nt][rr];
            } else {
                // final phase: deferred l reduction -> linv stash in dead UB half
                float* lp = (float*)(&UB[ntiles & 1][sw][0]);
                for (int rr = 0; rr < 4; ++rr) {
                    float v = lpart[rr];
                    v += __shfl_xor(v, 1);
                    v += __shfl_xor(v, 2);
                    v += __shfl_xor(v, 4);
                    v += __shfl_xor(v, 8);
                    lp[lane * 4 + rr] = 1.f / v;
                }
            }
            __builtin_amdgcn_s_setprio(0);
        } else if (p >= 1) {
            // O-waves: PV for tile p-1
            const bf16* Vl = Vs[(p - 1) & 1];
            const bf16* UBs = UB[(p - 1) & 1][sw];
            for (int c = 0; c < 2; ++c) {
                bf16x8 pa = *(const bf16x8*)(&UBs[l16 * 88 + c * 32 + quad * 8]);
                for (int nt = 0; nt < 4; ++nt) {
                    bf16x8 vb = frag8(Vl, nt * 16 + l16, c * 4 + quad);
                    oacc[nt] = MFMA16(pa, vb, oacc[nt]);
                }
            }
        }
        __syncthreads();  // DMA drain + UB handoff + buffer WAR
    }

    if (!isS) {
        const float* lp = (const float*)(&UB[ntiles & 1][sw][0]);
        for (int nt = 0; nt < 4; ++nt)
            for (int rr = 0; rr < 4; ++rr) {
                int i = i0 + sw * 16 + quad * 4 + rr;
                int d = nt * 16 + l16;
                AttO[((size_t)(b * QL + i)) * E + h * DH + d] =
                    (bf16)(oacc[nt][rr] * lp[lane * 4 + rr]);
            }
    }
}

// ---------------------------------------------------------------- out proj
// R18: split-K x4. 512 blocks -> 2 blocks/CU. z in 0..3 computes K-slice
// z*256..+256 -> partial Xp[z] (fp32); z==3 partial over dead WqT..WrT.
__global__ __launch_bounds__(256) void gemm_o(
    const bf16* __restrict__ A, const bf16* __restrict__ Bt,
    float* __restrict__ Xp, float* __restrict__ Xp3) {
    __shared__ __align__(16) bf16 As[128 * 64];
    __shared__ __align__(16) bf16 Bs[128 * 64];
    const int tid = threadIdx.x;
    const int wave = tid >> 6, lane = tid & 63, quad = lane >> 4, l16 = lane & 15;
    const int bm = blockIdx.y * 128, bn = blockIdx.x * 128;
    const int kbase = blockIdx.z * 256;
    const int wm = (wave >> 1) * 64, wn = (wave & 1) * 64;

    f32x4 acc[4][4] = {};

    for (int s = 0; s < 4; ++s) {
        const int kk = kbase + s * 64;
        for (int issue = 0; issue < 4; ++issue) {
            int q = (issue * 4 + wave) * 64 + lane;
            int row = q >> 3, cs = (q & 7) ^ ((q >> 3) & 7);
            ldg2lds16(A + (size_t)(bm + row) * E + kk + cs * 8,
                      As + (issue * 4 + wave) * 512);
            ldg2lds16(Bt + (size_t)(bn + row) * E + kk + cs * 8,
                      Bs + (issue * 4 + wave) * 512);
        }
        __syncthreads();
        for (int ks = 0; ks < 64; ks += 32) {
            bf16x8 af[4], bfr[4];
            for (int mt = 0; mt < 4; ++mt)
                af[mt] = frag8(As, wm + mt * 16 + l16, (ks >> 3) + quad);
            for (int nt = 0; nt < 4; ++nt)
                bfr[nt] = frag8(Bs, wn + nt * 16 + l16, (ks >> 3) + quad);
            for (int mt = 0; mt < 4; ++mt)
                for (int nt = 0; nt < 4; ++nt)
                    acc[mt][nt] = MFMA16(af[mt], bfr[nt], acc[mt][nt]);
        }
        __syncthreads();
    }

    float* Xz = (blockIdx.z == 3) ? Xp3
                                  : Xp + (size_t)blockIdx.z * 2048 * 1024;
    for (int mt = 0; mt < 4; ++mt)
        for (int nt = 0; nt < 4; ++nt)
            for (int rr = 0; rr < 4; ++rr) {
                int row = bm + wm + mt * 16 + quad * 4 + rr;
                int col = bn + wn + nt * 16 + l16;
                Xz[(size_t)row * E + col] = acc[mt][nt][rr];
            }
}

// ---------------------------------------------------------------- layernorm
// x = Xp0 + Xp1 + Xp2 + Xp3 + resid(w); out = LN(x)*gamma+beta
// R24: 512 blocks x 4 rows (per-row math identical to R23; float4 path).
__global__ __launch_bounds__(256) void ln_k(const float* __restrict__ Xp,
                                            const float* __restrict__ Xp3,
                                            const float* __restrict__ resid,
                                            const float* __restrict__ gamma,
                                            const float* __restrict__ beta,
                                            float* __restrict__ out) {
    const int tid = threadIdx.x;
    __shared__ float rs[4], rq[4];
    const int wave = tid >> 6, lane = tid & 63;
    float4 g = ((const float4*)gamma)[tid];
    float4 bt = ((const float4*)beta)[tid];
    for (int it = 0; it < 4; ++it) {
        const int row = blockIdx.x * 4 + it;
        const float4* x0 = (const float4*)(Xp + (size_t)row * E);
        const float4* x1 = (const float4*)(Xp + (size_t)2048 * 1024 + (size_t)row * E);
        const float4* x2 = (const float4*)(Xp + (size_t)2 * 2048 * 1024 + (size_t)row * E);
        const float4* x3 = (const float4*)(Xp3 + (size_t)row * E);
        const float4* xr = (const float4*)(resid + (size_t)row * E);
        float4 a0 = x0[tid], a1 = x1[tid], a2 = x2[tid], a3 = x3[tid], ar = xr[tid];
        float4 v;
        v.x = a0.x + a1.x + a2.x + a3.x + ar.x;
        v.y = a0.y + a1.y + a2.y + a3.y + ar.y;
        v.z = a0.z + a1.z + a2.z + a3.z + ar.z;
        v.w = a0.w + a1.w + a2.w + a3.w + ar.w;
        float s = v.x + v.y + v.z + v.w;
        float q = v.x * v.x + v.y * v.y + v.z * v.z + v.w * v.w;
        for (int off = 32; off > 0; off >>= 1) {
            s += __shfl_down(s, off);
            q += __shfl_down(q, off);
        }
        if (lane == 0) { rs[wave] = s; rq[wave] = q; }
        __syncthreads();
        float S = rs[0] + rs[1] + rs[2] + rs[3];
        float Q = rq[0] + rq[1] + rq[2] + rq[3];
        float mean = S * (1.f / E);
        float var = fmaxf(Q * (1.f / E) - mean * mean, 0.f);
        float rstd = rsqrtf(var + 1e-3f);
        float4 o;
        o.x = (v.x - mean) * rstd * g.x + bt.x;
        o.y = (v.y - mean) * rstd * g.y + bt.y;
        o.z = (v.z - mean) * rstd * g.z + bt.z;
        o.w = (v.w - mean) * rstd * g.w + bt.w;
        ((float4*)(out + (size_t)row * E))[tid] = o;
        __syncthreads();  // rs/rq reuse across rows
    }
}

// ---------------------------------------------------------------- launch
extern "C" void kernel_launch(void* const* d_in, const int* in_sizes, int n_in,
                              void* d_out, int out_size, void* d_ws,
                              size_t ws_size, hipStream_t stream) {
    (void)in_sizes; (void)n_in; (void)out_size; (void)ws_size;
    const float* w = (const float*)d_in[0];
    const float* r = (const float*)d_in[1];
    const float* rwb = (const float*)d_in[3];
    const float* rrb = (const float*)d_in[4];
    const float* member = (const float*)d_in[5];
    const float* Wq = (const float*)d_in[6];
    const float* Wk = (const float*)d_in[7];
    const float* Wv = (const float*)d_in[8];
    const float* Wr = (const float*)d_in[9];
    const float* Wo = (const float*)d_in[10];
    const float* gamma = (const float*)d_in[11];
    const float* beta = (const float*)d_in[12];
    float* out = (float*)d_out;

    char* ws = (char*)d_ws;
    const size_t MB = 1024 * 1024;
    bf16* WqT = (bf16*)(ws + 0 * MB);   // 0-8: WqT..WrT (dead after proj_k;
    bf16* WkT = (bf16*)(ws + 2 * MB);   //   reused as Xp3 by gemm_o)
    bf16* WvT = (bf16*)(ws + 4 * MB);
    bf16* WrT = (bf16*)(ws + 6 * MB);
    bf16* WoT = (bf16*)(ws + 8 * MB);   // live until gemm_o
    bf16* cat = (bf16*)(ws + 10 * MB);  // 10-18; dead after proj_k
    bf16* AttO = (bf16*)(ws + 14 * MB); // 14-18 (over cat 2nd half)
    bf16* Qw = (bf16*)(ws + 18 * MB);
    bf16* Qr = (bf16*)(ws + 22 * MB);
    float* Xp = (float*)(ws + 18 * MB); // 18-42: Xp z=0..2 (over Qw/Qr/Kh,
    bf16* Kh = (bf16*)(ws + 26 * MB);   //   dead after attn)
    bf16* Vt = (bf16*)(ws + 34 * MB);   // Vt dead after attn -> Xp z=2
    bf16* RRh = (bf16*)(ws + 42 * MB);
    float* Xp3 = (float*)(ws + 0 * MB); // z=3 partial over WqT..WrT
    // high-water: 46 MB (unchanged)

    pre_k<<<1792, 256, 0, stream>>>(Wq, Wk, Wv, Wr, Wo, member, w, WqT, WkT,
                                    WvT, WrT, WoT, cat);

    proj_k<<<768, 256, 0, stream>>>(cat, r, WqT, WkT, WvT, WrT, rwb, rrb, Qw,
                                    Qr, Kh, Vt, RRh);

    attn_k<<<512, 512, 0, stream>>>(Qw, Qr, Kh, Vt, RRh, AttO);

    gemm_o<<<dim3(8, 16, 4), 256, 0, stream>>>(AttO, WoT, Xp, Xp3);
    ln_k<<<512, 256, 0, stream>>>(Xp, Xp3, w, gamma, beta, out);
}